// Round 6
// baseline (30317.990 us; speedup 1.0000x reference)
//
#include <hip/hip_runtime.h>
#include <hip/hip_bf16.h>
#include <stdint.h>

typedef __attribute__((ext_vector_type(8))) short short8;
typedef __attribute__((ext_vector_type(4))) float f32x4;
typedef __attribute__((ext_vector_type(2))) float f32x2;

#define T_STEPS 512
#define BATCH   256
#define HDIM    1024
#define GDIM    4096   // 4*H
#define NGRP    8      // batch groups (32 rows each)
#define NJT     16     // j-tiles per group (64 j each)
#define GROWS   32
#define JSPAN   64

__device__ __forceinline__ float sigmoidf_(float v) {
  return 1.0f / (1.0f + __expf(-v));
}
__device__ __forceinline__ float tanh_(float v) {
  return 2.0f / (1.0f + __expf(-2.0f * v)) - 1.0f;
}
__device__ __forceinline__ short f2bf(float f) {
  __hip_bfloat16 h = __float2bfloat16(f);
  short s;
  __builtin_memcpy(&s, &h, 2);
  return s;
}

// coherent (MALL) 16B load: 32-bit VGPR byte offset + SGPR base
#define HL(dst, off, base)                                          \
  asm volatile("global_load_dwordx4 %0, %1, %2 sc0 sc1"             \
               : "=v"(dst) : "v"(off), "s"(base) : "memory")

// ---------------------------------------------------------------------------
// Pack: Whb=bf16(Wh), Wxb=bf16(Wx) [4096][1024]; biasc = bx + bh
// ---------------------------------------------------------------------------
__global__ void pack_kernel(const float* __restrict__ Wh, const float* __restrict__ Wx,
                            const float* __restrict__ bx, const float* __restrict__ bh,
                            __hip_bfloat16* __restrict__ Whb,
                            __hip_bfloat16* __restrict__ Wxb,
                            float* __restrict__ biasc)
{
  const int stride = gridDim.x * blockDim.x;
  const int tid0 = blockIdx.x * blockDim.x + threadIdx.x;
  for (int i = tid0; i < GDIM * HDIM; i += stride) {
    Whb[i] = __float2bfloat16(Wh[i]);
    Wxb[i] = __float2bfloat16(Wx[i]);
  }
  for (int i = tid0; i < GDIM; i += stride)
    biasc[i] = bx[i] + bh[i];
}

// ---------------------------------------------------------------------------
// Persistent LSTM: 128 blocks x 1024 thr (16 waves = 4 gates x 4 k-quarters).
// Block = (batch group g: 32 rows) x (j-tile jt: 64 j -> 256 gate-cols).
// Wh slice register-resident. Per step:
//   x-half (cached, barrier-independent)  ->  wait(gen>=s)  ->
//   coalesced sc0sc1 h stage -> LDS       ->  h-half MFMA   ->
//   k-quarter reduce in LDS               ->  cell + sc0sc1 h store -> arrive.
// bid mapping: g = bid>>4, jt = bid&15  => XCD (bid%8) hosts jt%8 pairs:
// Wx/Wh slices 1MB/XCD stay L2-resident [perf heuristic only].
// ---------------------------------------------------------------------------
__global__ __launch_bounds__(1024, 1)
void lstm_persist(const float* __restrict__ x,
                  const __hip_bfloat16* __restrict__ Whb,
                  const __hip_bfloat16* __restrict__ Wxb,
                  const float* __restrict__ biasc,
                  const float* __restrict__ c2c,
                  __hip_bfloat16* __restrict__ hb0,
                  __hip_bfloat16* __restrict__ hb1,
                  unsigned* __restrict__ bar)
{
  // red[4][32][260] f32 (133120 B); hstage (64 KB bf16 [32][1024] swizzled)
  // aliases the front — phases are barrier-separated.
  __shared__ __align__(16) float smem[33280];

  const int tid  = threadIdx.x;
  const int w    = tid >> 6;
  const int lane = tid & 63;
  const int l15  = lane & 15;
  const int lg   = lane >> 4;

  const int g  = blockIdx.x >> 4;   // batch group 0..7
  const int jt = blockIdx.x & 15;   // j tile 0..15
  const int b0 = g * GROWS;
  const int j0 = jt * JSPAN;

  const int cq = w >> 2;            // gate 0..3
  const int kq = w & 3;             // k-quarter 0..3

  // ---- persistent Wh fragments: bw[colfrag n][kchunk kc] ----
  short8 bw[4][8];
  const __hip_bfloat16* wxp[4];
#pragma unroll
  for (int n = 0; n < 4; ++n) {
    const size_t grow = (size_t)(cq * HDIM + j0 + n * 16 + l15);
    const __hip_bfloat16* wp = Whb + grow * HDIM + kq * 256 + lg * 8;
#pragma unroll
    for (int kc = 0; kc < 8; ++kc)
      bw[n][kc] = *(const short8*)(const void*)(wp + kc * 32);
    wxp[n] = Wxb + grow * HDIM + kq * 256 + lg * 8;
  }

  // ---- x-half sources (A rows = batch rows) ----
  const float* xbase0 = x + (size_t)(b0 + l15)      * T_STEPS * 1024 + kq * 256 + lg * 8;
  const float* xbase1 = x + (size_t)(b0 + 16 + l15) * T_STEPS * 1024 + kq * 256 + lg * 8;

  // ---- stage geometry (coalesced: lane-consecutive 16B) ----
  const int srow_b = w >> 1;              // + i*8 -> rows 0..31
  const int sg8    = (w & 1) * 64 + lane; // granule-col 0..127
  unsigned svoff[4];
  int      sslot[4];
#pragma unroll
  for (int i = 0; i < 4; ++i) {
    const int row = srow_b + i * 8;
    svoff[i] = (unsigned)(((b0 + row) * HDIM + sg8 * 8) * 2);
    sslot[i] = row * 128 + (sg8 ^ (row & 7));
  }

  // ---- epilogue mapping: thread owns (row ert, j ejj..ejj+1) ----
  const int ert = tid >> 5;
  const int ejj = (tid & 31) * 2;
  float bias0[4], bias1[4];
#pragma unroll
  for (int gg = 0; gg < 4; ++gg) {
    bias0[gg] = biasc[gg * HDIM + j0 + ejj];
    bias1[gg] = biasc[gg * HDIM + j0 + ejj + 1];
  }
  const float ci0 = c2c[j0 + ejj],            ci1 = c2c[j0 + ejj + 1];
  const float cf0 = c2c[HDIM + j0 + ejj],     cf1 = c2c[HDIM + j0 + ejj + 1];
  const float co0 = c2c[2 * HDIM + j0 + ejj], co1 = c2c[2 * HDIM + j0 + ejj + 1];
  const unsigned soff = (unsigned)(((b0 + ert) * HDIM + j0 + ejj) * 2);
  float cc0 = 0.f, cc1 = 0.f;

  const uint64_t hB0 = (uint64_t)hb0, hB1 = (uint64_t)hb1;
  unsigned* cnt = bar + (size_t)g * 32;
  unsigned* gen = bar + (size_t)(8 + g) * 32;

  short8* hstage = (short8*)smem;

#pragma unroll 1
  for (int s = 0; s < T_STEPS; ++s) {
    // =================== x-half (barrier-independent) ===================
    f32x4 acc[2][4];
#pragma unroll
    for (int m = 0; m < 2; ++m)
#pragma unroll
      for (int n = 0; n < 4; ++n) acc[m][n] = (f32x4){0.f, 0.f, 0.f, 0.f};

    const float* xp0 = xbase0 + (size_t)s * 1024;
    const float* xp1 = xbase1 + (size_t)s * 1024;
#pragma unroll
    for (int kc = 0; kc < 8; ++kc) {
      f32x4 a0l = *(const f32x4*)(xp0 + kc * 32);
      f32x4 a0h = *(const f32x4*)(xp0 + kc * 32 + 4);
      f32x4 a1l = *(const f32x4*)(xp1 + kc * 32);
      f32x4 a1h = *(const f32x4*)(xp1 + kc * 32 + 4);
      short8 wv0 = *(const short8*)(const void*)(wxp[0] + kc * 32);
      short8 wv1 = *(const short8*)(const void*)(wxp[1] + kc * 32);
      short8 wv2 = *(const short8*)(const void*)(wxp[2] + kc * 32);
      short8 wv3 = *(const short8*)(const void*)(wxp[3] + kc * 32);
      short8 xa0, xa1;
#pragma unroll
      for (int e = 0; e < 4; ++e) {
        xa0[e] = f2bf(a0l[e]); xa0[e + 4] = f2bf(a0h[e]);
        xa1[e] = f2bf(a1l[e]); xa1[e + 4] = f2bf(a1h[e]);
      }
      acc[0][0] = __builtin_amdgcn_mfma_f32_16x16x32_bf16(xa0, wv0, acc[0][0], 0, 0, 0);
      acc[0][1] = __builtin_amdgcn_mfma_f32_16x16x32_bf16(xa0, wv1, acc[0][1], 0, 0, 0);
      acc[0][2] = __builtin_amdgcn_mfma_f32_16x16x32_bf16(xa0, wv2, acc[0][2], 0, 0, 0);
      acc[0][3] = __builtin_amdgcn_mfma_f32_16x16x32_bf16(xa0, wv3, acc[0][3], 0, 0, 0);
      acc[1][0] = __builtin_amdgcn_mfma_f32_16x16x32_bf16(xa1, wv0, acc[1][0], 0, 0, 0);
      acc[1][1] = __builtin_amdgcn_mfma_f32_16x16x32_bf16(xa1, wv1, acc[1][1], 0, 0, 0);
      acc[1][2] = __builtin_amdgcn_mfma_f32_16x16x32_bf16(xa1, wv2, acc[1][2], 0, 0, 0);
      acc[1][3] = __builtin_amdgcn_mfma_f32_16x16x32_bf16(xa1, wv3, acc[1][3], 0, 0, 0);
    }

    // =================== wait for h(s) ===================
    if (s > 0 && tid == 0) {
      while (__hip_atomic_load(gen, __ATOMIC_RELAXED, __HIP_MEMORY_SCOPE_SYSTEM) < (unsigned)s)
        __builtin_amdgcn_s_sleep(1);
    }
    __syncthreads();   // release smem from prev epilogue; gate on gen

    // =================== stage h -> LDS (coalesced sc0sc1) ===================
    {
      const uint64_t hbase = (s & 1) ? hB1 : hB0;
      short8 hv0, hv1, hv2, hv3;
      HL(hv0, svoff[0], hbase);
      HL(hv1, svoff[1], hbase);
      HL(hv2, svoff[2], hbase);
      HL(hv3, svoff[3], hbase);
      asm volatile("s_waitcnt vmcnt(0)" ::: "memory");
      hstage[sslot[0]] = hv0;
      hstage[sslot[1]] = hv1;
      hstage[sslot[2]] = hv2;
      hstage[sslot[3]] = hv3;
    }
    __syncthreads();

    // =================== h-half MFMA from LDS ===================
#pragma unroll
    for (int m = 0; m < 2; ++m) {
      const int arow = m * 16 + l15;
      const int abase = arow * 128;
      const int a7 = arow & 7;
#pragma unroll
      for (int kc = 0; kc < 8; ++kc) {
        short8 af = hstage[abase + ((kq * 32 + kc * 4 + lg) ^ a7)];
        acc[m][0] = __builtin_amdgcn_mfma_f32_16x16x32_bf16(af, bw[0][kc], acc[m][0], 0, 0, 0);
        acc[m][1] = __builtin_amdgcn_mfma_f32_16x16x32_bf16(af, bw[1][kc], acc[m][1], 0, 0, 0);
        acc[m][2] = __builtin_amdgcn_mfma_f32_16x16x32_bf16(af, bw[2][kc], acc[m][2], 0, 0, 0);
        acc[m][3] = __builtin_amdgcn_mfma_f32_16x16x32_bf16(af, bw[3][kc], acc[m][3], 0, 0, 0);
      }
    }
    __syncthreads();   // hstage reads done before red overwrites

    // =================== k-quarter partials -> red ===================
#pragma unroll
    for (int m = 0; m < 2; ++m)
#pragma unroll
      for (int n = 0; n < 4; ++n)
#pragma unroll
        for (int r = 0; r < 4; ++r)
          smem[kq * 8320 + (m * 16 + lg * 4 + r) * 260 + cq * 64 + n * 16 + l15] =
              acc[m][n][r];
    __syncthreads();

    // =================== cell + h store ===================
    {
      float gq0[4], gq1[4];
#pragma unroll
      for (int gg = 0; gg < 4; ++gg) {
        float a0 = bias0[gg], a1 = bias1[gg];
#pragma unroll
        for (int q = 0; q < 4; ++q) {
          f32x2 v = *(const f32x2*)&smem[q * 8320 + ert * 260 + gg * 64 + ejj];
          a0 += v[0];
          a1 += v[1];
        }
        gq0[gg] = a0; gq1[gg] = a1;
      }
      float ii = sigmoidf_(gq0[0] + ci0 * cc0);
      float ff = sigmoidf_(gq0[1] + cf0 * cc0);
      float gv = tanh_(gq0[2]);
      float cn = ff * cc0 + ii * gv;
      float oo = sigmoidf_(gq0[3] + co0 * cn);
      float hh0 = oo * tanh_(cn);
      cc0 = cn;
      ii = sigmoidf_(gq1[0] + ci1 * cc1);
      ff = sigmoidf_(gq1[1] + cf1 * cc1);
      gv = tanh_(gq1[2]);
      cn = ff * cc1 + ii * gv;
      oo = sigmoidf_(gq1[3] + co1 * cn);
      float hh1 = oo * tanh_(cn);
      cc1 = cn;
      unsigned pk = (unsigned)(unsigned short)f2bf(hh0) |
                    ((unsigned)(unsigned short)f2bf(hh1) << 16);
      const uint64_t sbase = (s & 1) ? hB0 : hB1;
      asm volatile("global_store_dword %0, %1, %2 sc0 sc1"
                   :: "v"(soff), "v"(pk), "s"(sbase) : "memory");
      asm volatile("s_waitcnt vmcnt(0)" ::: "memory");
    }
    __syncthreads();   // all h stores drained before arrive

    // =================== arrive ===================
    if (s < T_STEPS - 1 && tid == 0) {
      unsigned old = __hip_atomic_fetch_add(cnt, 1u, __ATOMIC_RELAXED,
                                            __HIP_MEMORY_SCOPE_SYSTEM);
      if ((old & 15u) == 15u)
        __hip_atomic_fetch_add(gen, 1u, __ATOMIC_RELAXED, __HIP_MEMORY_SCOPE_SYSTEM);
    }
  }
}

// ---------------------------------------------------------------------------
// Final FC: out[b][o] = h[b][:] . Wfc[o][:] + bfc[o]  (M=256,N=1024,K=1024)
// ---------------------------------------------------------------------------
__global__ __launch_bounds__(256, 1)
void fc_kernel(const __hip_bfloat16* __restrict__ h,
               const float* __restrict__ Wfc,
               const float* __restrict__ bfc,
               float* __restrict__ out)
{
  __shared__ short8 As8[512];
  __shared__ short8 Bs8[512];

  const int tid = threadIdx.x;
  const int wave = tid >> 6;
  const int lane = tid & 63;
  const int mtile = blockIdx.x >> 4;
  const int otile = blockIdx.x & 15;
  const int b0 = mtile * 64, o0 = otile * 64;

  const int r0 = tid >> 3;
  const int cg0 = tid & 7;

  f32x4 acc[4];
#pragma unroll
  for (int f = 0; f < 4; ++f) acc[f] = (f32x4){0.f, 0.f, 0.f, 0.f};

#pragma unroll 1
  for (int kc = 0; kc < 16; ++kc) {
    __syncthreads();
    As8[r0 * 8 + (cg0 ^ (r0 & 7))] =
        *(const short8*)(const void*)(h + (size_t)(b0 + r0) * HDIM + kc * 64 + cg0 * 8);
    As8[(r0 + 32) * 8 + (cg0 ^ (r0 & 7))] =
        *(const short8*)(const void*)(h + (size_t)(b0 + r0 + 32) * HDIM + kc * 64 + cg0 * 8);
    {
      const float* p0 = Wfc + (size_t)(o0 + r0) * HDIM + kc * 64 + cg0 * 8;
      const float* p1 = Wfc + (size_t)(o0 + r0 + 32) * HDIM + kc * 64 + cg0 * 8;
      f32x4 l0 = *(const f32x4*)p0, h0 = *(const f32x4*)(p0 + 4);
      f32x4 l1 = *(const f32x4*)p1, h1 = *(const f32x4*)(p1 + 4);
      short8 s0, s1;
#pragma unroll
      for (int e = 0; e < 4; ++e) {
        s0[e] = f2bf(l0[e]); s0[e + 4] = f2bf(h0[e]);
        s1[e] = f2bf(l1[e]); s1[e + 4] = f2bf(h1[e]);
      }
      Bs8[r0 * 8 + (cg0 ^ (r0 & 7))] = s0;
      Bs8[(r0 + 32) * 8 + (cg0 ^ (r0 & 7))] = s1;
    }
    __syncthreads();
#pragma unroll
    for (int s = 0; s < 2; ++s) {
      const int colg = s * 4 + (lane >> 4);
      const int ar = wave * 16 + (lane & 15);
      short8 af = As8[ar * 8 + (colg ^ (ar & 7))];
#pragma unroll
      for (int f = 0; f < 4; ++f) {
        const int br = f * 16 + (lane & 15);
        short8 bfq = Bs8[br * 8 + (colg ^ (br & 7))];
        acc[f] = __builtin_amdgcn_mfma_f32_16x16x32_bf16(af, bfq, acc[f], 0, 0, 0);
      }
    }
  }

  const int dcol = lane & 15;
  const int drow = (lane >> 4) * 4;
#pragma unroll
  for (int f = 0; f < 4; ++f) {
    const int o = o0 + f * 16 + dcol;
    const float bias = bfc[o];
#pragma unroll
    for (int r = 0; r < 4; ++r) {
      const int b = b0 + wave * 16 + drow + r;
      out[(size_t)b * 1024 + o] = acc[f][r] + bias;
    }
  }
}

// ---------------------------------------------------------------------------
extern "C" void kernel_launch(void* const* d_in, const int* in_sizes, int n_in,
                              void* d_out, int out_size, void* d_ws, size_t ws_size,
                              hipStream_t stream)
{
  const float* x   = (const float*)d_in[0];
  const float* Wx  = (const float*)d_in[1];
  const float* bx  = (const float*)d_in[2];
  const float* Wh  = (const float*)d_in[3];
  const float* bh  = (const float*)d_in[4];
  const float* c2c = (const float*)d_in[5];
  const float* Wfc = (const float*)d_in[6];
  const float* bfc = (const float*)d_in[7];
  float* out = (float*)d_out;

  char* ws = (char*)d_ws;
  // layout: Whb [0,8M) | Wxb [8M,16M) | biasc @16M (16K)
  //         hb0 @16M+64K (512K) | hb1 +512K | bar @17M+64K (4K)
  __hip_bfloat16* Whb   = (__hip_bfloat16*)(ws);
  __hip_bfloat16* Wxb   = (__hip_bfloat16*)(ws + (8u << 20));
  float*          biasc = (float*)(ws + (16u << 20));
  __hip_bfloat16* hb0   = (__hip_bfloat16*)(ws + (16u << 20) + (1u << 16));
  __hip_bfloat16* hb1   = (__hip_bfloat16*)(ws + (16u << 20) + (1u << 16) + (1u << 19));
  unsigned*       bar   = (unsigned*)(ws + (17u << 20) + (1u << 16));

  hipMemsetAsync(hb0, 0, (size_t)BATCH * HDIM * sizeof(__hip_bfloat16), stream);
  hipMemsetAsync(bar, 0, 4096, stream);

  pack_kernel<<<1024, 256, 0, stream>>>(Wh, Wx, bx, bh, Whb, Wxb, biasc);

  {
    const float* xa = x;
    const __hip_bfloat16* wha = Whb;
    const __hip_bfloat16* wxa = Wxb;
    const float* ba = biasc;
    const float* ca = c2c;
    __hip_bfloat16* h0a = hb0;
    __hip_bfloat16* h1a = hb1;
    unsigned* bara = bar;
    void* args[] = { (void*)&xa, (void*)&wha, (void*)&wxa, (void*)&ba,
                     (void*)&ca, (void*)&h0a, (void*)&h1a, (void*)&bara };
    hipLaunchCooperativeKernel((const void*)lstm_persist, dim3(128), dim3(1024),
                               args, 0, stream);
  }

  fc_kernel<<<64, 256, 0, stream>>>(hb0, Wfc, bfc, out);
}

// Round 7
// 17650.499 us; speedup vs baseline: 1.7177x; 1.7177x over previous
//
#include <hip/hip_runtime.h>
#include <hip/hip_bf16.h>
#include <stdint.h>

typedef __attribute__((ext_vector_type(8))) short short8;
typedef __attribute__((ext_vector_type(4))) float f32x4;

#define T_STEPS 512
#define HDIM    1024

__device__ __forceinline__ float sigmoidf_(float v) {
  return 1.0f / (1.0f + __expf(-v));
}
__device__ __forceinline__ float tanh_(float v) {
  return 2.0f / (1.0f + __expf(-2.0f * v)) - 1.0f;
}
__device__ __forceinline__ short f2bf(float f) {
  __hip_bfloat16 h = __float2bfloat16(f);
  short s;
  __builtin_memcpy(&s, &h, 2);
  return s;
}
__device__ __forceinline__ float bf2f(unsigned u16) {
  unsigned u = u16 << 16;
  float f;
  __builtin_memcpy(&f, &u, 4);
  return f;
}

// sc0: bypass L1, hit L2 (XCD-local coherent h exchange)
#define HL(dst, off, base)                                          \
  asm volatile("global_load_dwordx4 %0, %1, %2 sc0"                 \
               : "=v"(dst) : "v"(off), "s"(base) : "memory")
// sc0 sc1: MALL-coherent (cross-XCD ring)
#define RL(dst, off, base)                                          \
  asm volatile("global_load_dwordx4 %0, %1, %2 sc0 sc1"             \
               : "=v"(dst) : "v"(off), "s"(base) : "memory")
#define RS(off, val, base)                                          \
  asm volatile("global_store_dwordx4 %0, %1, %2 sc0 sc1"            \
               :: "v"(off), "v"(val), "s"(base) : "memory")

// ---------------------------------------------------------------------------
// Pack: Wxb=bf16(Wx) [4096][1024]; biasc = bx + bh
// ---------------------------------------------------------------------------
__global__ void pack_kernel(const float* __restrict__ Wx,
                            const float* __restrict__ bx, const float* __restrict__ bh,
                            __hip_bfloat16* __restrict__ Wxb,
                            float* __restrict__ biasc)
{
  const int stride = gridDim.x * blockDim.x;
  const int tid0 = blockIdx.x * blockDim.x + threadIdx.x;
  for (int i = tid0; i < 4096 * 1024; i += stride)
    Wxb[i] = __float2bfloat16(Wx[i]);
  for (int i = tid0; i < 4096; i += stride)
    biasc[i] = bx[i] + bh[i];
}

// ---------------------------------------------------------------------------
// Persistent LSTM, 256 blocks x 512 thr, cooperative, XCD-self-organized.
// Consumer split: XCD g = batch rows [32g,32g+32); slot jt = 32 j-cols x 4
// gates (Wh slice 256 KB in REGISTERS, 128 VGPR/wave at 8 waves).
// h exchange: normal write-through stores + sc0 loads, XCD-local L2 only.
// Producer split (xg = x@Wx^T, 2 steps ahead): tile 64 rows x 64 cols,
// m2 = slot>>3, n2 = g*8+(slot&7) -> per-XCD Wx slice 1 MB (L2-resident);
// handoff via 4-slot MALL ring (sc0sc1), placed between barrier arrive/wait.
// One global barrier per step (monotonic cnt/gen at MALL), NO fences.
// ---------------------------------------------------------------------------
__global__ __launch_bounds__(512, 2)
void lstm_persist(const float* __restrict__ x,
                  const float* __restrict__ Wh,     // fp32 [4096][1024]
                  const __hip_bfloat16* __restrict__ Wxb,
                  const float* __restrict__ biasc,
                  const float* __restrict__ c2c,
                  __hip_bfloat16* __restrict__ hbuf,  // [2][256][1024]
                  __hip_bfloat16* __restrict__ ring,  // [4][256][4096]
                  unsigned* __restrict__ bar)
{
  __shared__ short8 hstage[4096];          // 64 KB: h[32][1024] swizzled
  __shared__ float red[4608];              // 18 KB: gates [4][32][36]
  __shared__ float predp[4352];            // 17 KB: producer partials [64][68]
  __shared__ unsigned short packb[4608];   //  9 KB: producer bf16 out [64][72]
  __shared__ unsigned short xstage[4352];  //  8.5 KB: xg tile [32][136]
  __shared__ int sh_xcd, sh_slot;

  const int tid  = threadIdx.x;
  const int w    = tid >> 6;
  const int lane = tid & 63;
  const int l15  = lane & 15;
  const int lg   = lane >> 4;

  // ---- self-organize: physical XCD + claimed slot ----
  if (tid == 0) {
    unsigned xcc;
    asm volatile("s_getreg_b32 %0, hwreg(HW_REG_XCC_ID)" : "=s"(xcc));
    int xcd = (int)(xcc & 7u);
    unsigned sl = __hip_atomic_fetch_add(&bar[32 + xcd * 16], 1u,
                                         __ATOMIC_RELAXED, __HIP_MEMORY_SCOPE_SYSTEM);
    sh_xcd = xcd;
    sh_slot = (int)(sl & 31u);
  }
  __syncthreads();
  const int g  = sh_xcd;    // batch group == XCD
  const int jt = sh_slot;   // j-tile 0..31

  const int gate = w >> 1;  // 0..3 (also producer row-frag)
  const int kh   = w & 1;   // k-half

  // ---- consumer: Wh slice -> registers (fp32 -> bf16, one time) ----
  short8 bw0[16], bw1[16];
  {
    const float* wb = Wh + (size_t)(gate * 1024 + jt * 32 + l15) * HDIM + kh * 512 + lg * 8;
#pragma unroll
    for (int c = 0; c < 16; ++c) {
      f32x4 a = *(const f32x4*)(wb + c * 32);
      f32x4 b = *(const f32x4*)(wb + c * 32 + 4);
      short8 v;
#pragma unroll
      for (int e = 0; e < 4; ++e) { v[e] = f2bf(a[e]); v[e + 4] = f2bf(b[e]); }
      bw0[c] = v;
      a = *(const f32x4*)(wb + 16 * HDIM + c * 32);
      b = *(const f32x4*)(wb + 16 * HDIM + c * 32 + 4);
#pragma unroll
      for (int e = 0; e < 4; ++e) { v[e] = f2bf(a[e]); v[e + 4] = f2bf(b[e]); }
      bw1[c] = v;
    }
  }

  // ---- h stage geometry (8 x 16B per thread, coalesced) ----
  unsigned hvoff[8];
  int hslot[8];
#pragma unroll
  for (int i = 0; i < 8; ++i) {
    const int idx = tid + i * 512;
    const int row = idx >> 7, col = idx & 127;
    hvoff[i] = (unsigned)(((g * 32 + row) * 1024 + col * 8) * 2);
    hslot[i] = row * 128 + (col ^ (row & 7));
  }

  // ---- ring read geometry (1 x 16B per thread) ----
  const int rr   = tid >> 4;
  const int rseg = tid & 15;
  const unsigned rdoff =
      (unsigned)((((g * 32 + rr) * 4096) + (rseg >> 2) * 1024 + jt * 32 + (rseg & 3) * 8) * 2);
  const int xslot = rr * 17 + rseg;

  // ---- producer geometry ----
  const int m2 = jt >> 3;
  const int n2 = g * 8 + (jt & 7);
  const int prow = tid >> 3, pseg = tid & 7;
  const unsigned rsoff = (unsigned)((((m2 * 64 + prow) * 4096) + n2 * 64 + pseg * 8) * 2);

  // ---- cell constants ----
  const int er = tid >> 4;          // 0..31 batch row in group
  const int ej = (tid & 15) * 2;    // j pair
  const int jj = jt * 32 + ej;
  float b0_[4], b1_[4];
#pragma unroll
  for (int gg = 0; gg < 4; ++gg) {
    b0_[gg] = biasc[gg * 1024 + jj];
    b1_[gg] = biasc[gg * 1024 + jj + 1];
  }
  const float ci0 = c2c[jj],        ci1 = c2c[jj + 1];
  const float cf0 = c2c[1024 + jj], cf1 = c2c[1024 + jj + 1];
  const float co0 = c2c[2048 + jj], co1 = c2c[2048 + jj + 1];
  const int hout_off = (g * 32 + er) * 1024 + jj;
  float cc0 = 0.f, cc1 = 0.f;

  const uint64_t hb64 = (uint64_t)hbuf;
  const uint64_t ring64 = (uint64_t)ring;
  unsigned* cntp = bar;
  unsigned* genp = bar + 16;

#define PRODUCE(T, SLOT)                                                       \
  do {                                                                         \
    f32x4 ap0 = {0,0,0,0}, ap1 = {0,0,0,0}, ap2 = {0,0,0,0}, ap3 = {0,0,0,0};  \
    const float* xb_ = x + ((size_t)(m2 * 64 + gate * 16 + l15) * T_STEPS + (size_t)(T)) * 1024 \
                         + kh * 512 + lg * 8;                                  \
    const __hip_bfloat16* wb_ = Wxb + (size_t)(n2 * 64 + l15) * 1024 + kh * 512 + lg * 8; \
    _Pragma("unroll")                                                          \
    for (int c = 0; c < 16; ++c) {                                             \
      f32x4 xl_ = *(const f32x4*)(xb_ + c * 32);                               \
      f32x4 xh_ = *(const f32x4*)(xb_ + c * 32 + 4);                           \
      short8 w0_ = *(const short8*)(const void*)(wb_ + c * 32);                \
      short8 w1_ = *(const short8*)(const void*)(wb_ + 16384 + c * 32);        \
      short8 w2_ = *(const short8*)(const void*)(wb_ + 32768 + c * 32);        \
      short8 w3_ = *(const short8*)(const void*)(wb_ + 49152 + c * 32);        \
      short8 xa_;                                                              \
      _Pragma("unroll")                                                        \
      for (int e = 0; e < 4; ++e) { xa_[e] = f2bf(xl_[e]); xa_[e + 4] = f2bf(xh_[e]); } \
      ap0 = __builtin_amdgcn_mfma_f32_16x16x32_bf16(xa_, w0_, ap0, 0, 0, 0);   \
      ap1 = __builtin_amdgcn_mfma_f32_16x16x32_bf16(xa_, w1_, ap1, 0, 0, 0);   \
      ap2 = __builtin_amdgcn_mfma_f32_16x16x32_bf16(xa_, w2_, ap2, 0, 0, 0);   \
      ap3 = __builtin_amdgcn_mfma_f32_16x16x32_bf16(xa_, w3_, ap3, 0, 0, 0);   \
    }                                                                          \
    if (kh == 1) {                                                             \
      _Pragma("unroll")                                                        \
      for (int r = 0; r < 4; ++r) {                                            \
        const int rw_ = (gate * 16 + lg * 4 + r) * 68;                         \
        predp[rw_ + l15]      = ap0[r];                                        \
        predp[rw_ + 16 + l15] = ap1[r];                                        \
        predp[rw_ + 32 + l15] = ap2[r];                                        \
        predp[rw_ + 48 + l15] = ap3[r];                                        \
      }                                                                        \
    }                                                                          \
    __syncthreads();                                                           \
    if (kh == 0) {                                                             \
      _Pragma("unroll")                                                        \
      for (int r = 0; r < 4; ++r) {                                            \
        const int rw_ = (gate * 16 + lg * 4 + r) * 68;                         \
        const int pw_ = (gate * 16 + lg * 4 + r) * 72;                         \
        packb[pw_ + l15]      = (unsigned short)f2bf(ap0[r] + predp[rw_ + l15]);      \
        packb[pw_ + 16 + l15] = (unsigned short)f2bf(ap1[r] + predp[rw_ + 16 + l15]); \
        packb[pw_ + 32 + l15] = (unsigned short)f2bf(ap2[r] + predp[rw_ + 32 + l15]); \
        packb[pw_ + 48 + l15] = (unsigned short)f2bf(ap3[r] + predp[rw_ + 48 + l15]); \
      }                                                                        \
    }                                                                          \
    __syncthreads();                                                           \
    {                                                                          \
      short8 pv_ = *(const short8*)(const void*)&packb[prow * 72 + pseg * 8];  \
      RS(rsoff, pv_, ring64 + (uint64_t)(SLOT) * 2097152u);                    \
    }                                                                          \
  } while (0)

  // ---- prologue: prime ring with xg(0), xg(1) ----
  PRODUCE(0, 0);
  PRODUCE(1, 1);
  asm volatile("s_waitcnt vmcnt(0)" ::: "memory");
  __syncthreads();
  if (tid == 0) {
    unsigned old = __hip_atomic_fetch_add(cntp, 1u, __ATOMIC_RELAXED, __HIP_MEMORY_SCOPE_SYSTEM);
    if ((old & 255u) == 255u)
      __hip_atomic_fetch_add(genp, 1u, __ATOMIC_RELAXED, __HIP_MEMORY_SCOPE_SYSTEM);
    while (__hip_atomic_load(genp, __ATOMIC_RELAXED, __HIP_MEMORY_SCOPE_SYSTEM) < 1u)
      __builtin_amdgcn_s_sleep(1);
  }
  __syncthreads();

#pragma unroll 1
  for (int s = 0; s < T_STEPS; ++s) {
    // ---- issue ring(xg(s)) + h(s) loads; stage to LDS ----
    {
      short8 rv, hv0, hv1, hv2, hv3, hv4, hv5, hv6, hv7;
      RL(rv, rdoff, ring64 + (uint64_t)(s & 3) * 2097152u);
      const uint64_t hb = hb64 + (uint64_t)(s & 1) * 524288u;
      HL(hv0, hvoff[0], hb); HL(hv1, hvoff[1], hb);
      HL(hv2, hvoff[2], hb); HL(hv3, hvoff[3], hb);
      HL(hv4, hvoff[4], hb); HL(hv5, hvoff[5], hb);
      HL(hv6, hvoff[6], hb); HL(hv7, hvoff[7], hb);
      asm volatile("s_waitcnt vmcnt(0)" ::: "memory");
      ((short8*)xstage)[xslot] = rv;
      hstage[hslot[0]] = hv0; hstage[hslot[1]] = hv1;
      hstage[hslot[2]] = hv2; hstage[hslot[3]] = hv3;
      hstage[hslot[4]] = hv4; hstage[hslot[5]] = hv5;
      hstage[hslot[6]] = hv6; hstage[hslot[7]] = hv7;
    }
    __syncthreads();

    // ---- h-GEMM: A from LDS, B from registers ----
    f32x4 acc00 = {0,0,0,0}, acc01 = {0,0,0,0}, acc10 = {0,0,0,0}, acc11 = {0,0,0,0};
    {
      const int a0b = l15 * 128, a1b = (16 + l15) * 128;
      const int sx = l15 & 7;
      const int kb = kh * 64;
#pragma unroll
      for (int c = 0; c < 16; ++c) {
        short8 a0 = hstage[a0b + ((kb + c * 4 + lg) ^ sx)];
        short8 a1 = hstage[a1b + ((kb + c * 4 + lg) ^ sx)];
        acc00 = __builtin_amdgcn_mfma_f32_16x16x32_bf16(a0, bw0[c], acc00, 0, 0, 0);
        acc01 = __builtin_amdgcn_mfma_f32_16x16x32_bf16(a0, bw1[c], acc01, 0, 0, 0);
        acc10 = __builtin_amdgcn_mfma_f32_16x16x32_bf16(a1, bw0[c], acc10, 0, 0, 0);
        acc11 = __builtin_amdgcn_mfma_f32_16x16x32_bf16(a1, bw1[c], acc11, 0, 0, 0);
      }
    }
    __syncthreads();   // hstage reads done (safe vs next-iter overwrite via later syncs)

    // ---- k-half reduce ----
    if (kh == 1) {
#pragma unroll
      for (int r = 0; r < 4; ++r) {
        const int rw = gate * 1152 + (lg * 4 + r) * 36;
        red[rw + l15] = acc00[r];
        red[rw + 16 + l15] = acc01[r];
        red[rw + 16 * 36 + l15] = acc10[r];
        red[rw + 16 * 36 + 16 + l15] = acc11[r];
      }
    }
    __syncthreads();
    if (kh == 0) {
#pragma unroll
      for (int r = 0; r < 4; ++r) {
        const int rw = gate * 1152 + (lg * 4 + r) * 36;
        red[rw + l15] += acc00[r];
        red[rw + 16 + l15] += acc01[r];
        red[rw + 16 * 36 + l15] += acc10[r];
        red[rw + 16 * 36 + 16 + l15] += acc11[r];
      }
    }
    __syncthreads();

    // ---- cell (all 512 threads, 2 cells each) + h store (normal, L2-local) ----
    {
      float gv0[4], gv1[4];
#pragma unroll
      for (int gg = 0; gg < 4; ++gg) {
        unsigned u = *(const unsigned*)&xstage[er * 136 + gg * 32 + ej];
        const float* rp = &red[gg * 1152 + er * 36 + ej];
        gv0[gg] = rp[0] + bf2f(u & 0xffffu) + b0_[gg];
        gv1[gg] = rp[1] + bf2f(u >> 16) + b1_[gg];
      }
      float ii = sigmoidf_(gv0[0] + ci0 * cc0);
      float ff = sigmoidf_(gv0[1] + cf0 * cc0);
      float gv = tanh_(gv0[2]);
      float cn = ff * cc0 + ii * gv;
      float oo = sigmoidf_(gv0[3] + co0 * cn);
      float h0 = oo * tanh_(cn);
      cc0 = cn;
      ii = sigmoidf_(gv1[0] + ci1 * cc1);
      ff = sigmoidf_(gv1[1] + cf1 * cc1);
      gv = tanh_(gv1[2]);
      cn = ff * cc1 + ii * gv;
      oo = sigmoidf_(gv1[3] + co1 * cn);
      float h1 = oo * tanh_(cn);
      cc1 = cn;
      unsigned pk = (unsigned)(unsigned short)f2bf(h0) |
                    ((unsigned)(unsigned short)f2bf(h1) << 16);
      *(unsigned*)(hbuf + ((s + 1) & 1) * 262144 + hout_off) = pk;
    }

    if (s == T_STEPS - 1) break;

    __syncthreads();   // drains h stores (compiler emits vmcnt(0) before barrier)
    if (tid == 0)
      (void)({ unsigned old = __hip_atomic_fetch_add(cntp, 1u, __ATOMIC_RELAXED,
                                                     __HIP_MEMORY_SCOPE_SYSTEM);
               if ((old & 255u) == 255u)
                 __hip_atomic_fetch_add(genp, 1u, __ATOMIC_RELAXED,
                                        __HIP_MEMORY_SCOPE_SYSTEM);
               0; });

    if (s < T_STEPS - 2)
      PRODUCE(s + 2, (s + 2) & 3);   // hides barrier latency

    if (tid == 0) {
      const unsigned tgt = (unsigned)(s + 2);
      while (__hip_atomic_load(genp, __ATOMIC_RELAXED, __HIP_MEMORY_SCOPE_SYSTEM) < tgt)
        __builtin_amdgcn_s_sleep(1);
    }
    __syncthreads();
  }
#undef PRODUCE
}

// ---------------------------------------------------------------------------
// Final FC: out[b][o] = h[b][:] . Wfc[o][:] + bfc[o]  (M=256,N=1024,K=1024)
// ---------------------------------------------------------------------------
__global__ __launch_bounds__(256, 1)
void fc_kernel(const __hip_bfloat16* __restrict__ h,
               const float* __restrict__ Wfc,
               const float* __restrict__ bfc,
               float* __restrict__ out)
{
  __shared__ short8 As8[512];
  __shared__ short8 Bs8[512];

  const int tid = threadIdx.x;
  const int wave = tid >> 6;
  const int lane = tid & 63;
  const int mtile = blockIdx.x >> 4;
  const int otile = blockIdx.x & 15;
  const int b0 = mtile * 64, o0 = otile * 64;

  const int r0 = tid >> 3;
  const int cg0 = tid & 7;

  f32x4 acc[4];
#pragma unroll
  for (int f = 0; f < 4; ++f) acc[f] = (f32x4){0.f, 0.f, 0.f, 0.f};

#pragma unroll 1
  for (int kc = 0; kc < 16; ++kc) {
    __syncthreads();
    As8[r0 * 8 + (cg0 ^ (r0 & 7))] =
        *(const short8*)(const void*)(h + (size_t)(b0 + r0) * HDIM + kc * 64 + cg0 * 8);
    As8[(r0 + 32) * 8 + (cg0 ^ (r0 & 7))] =
        *(const short8*)(const void*)(h + (size_t)(b0 + r0 + 32) * HDIM + kc * 64 + cg0 * 8);
    {
      const float* p0 = Wfc + (size_t)(o0 + r0) * HDIM + kc * 64 + cg0 * 8;
      const float* p1 = Wfc + (size_t)(o0 + r0 + 32) * HDIM + kc * 64 + cg0 * 8;
      f32x4 l0 = *(const f32x4*)p0, h0 = *(const f32x4*)(p0 + 4);
      f32x4 l1 = *(const f32x4*)p1, h1 = *(const f32x4*)(p1 + 4);
      short8 s0, s1;
#pragma unroll
      for (int e = 0; e < 4; ++e) {
        s0[e] = f2bf(l0[e]); s0[e + 4] = f2bf(h0[e]);
        s1[e] = f2bf(l1[e]); s1[e + 4] = f2bf(h1[e]);
      }
      Bs8[r0 * 8 + (cg0 ^ (r0 & 7))] = s0;
      Bs8[(r0 + 32) * 8 + (cg0 ^ (r0 & 7))] = s1;
    }
    __syncthreads();
#pragma unroll
    for (int s = 0; s < 2; ++s) {
      const int colg = s * 4 + (lane >> 4);
      const int ar = wave * 16 + (lane & 15);
      short8 af = As8[ar * 8 + (colg ^ (ar & 7))];
#pragma unroll
      for (int f = 0; f < 4; ++f) {
        const int br = f * 16 + (lane & 15);
        short8 bfq = Bs8[br * 8 + (colg ^ (br & 7))];
        acc[f] = __builtin_amdgcn_mfma_f32_16x16x32_bf16(af, bfq, acc[f], 0, 0, 0);
      }
    }
  }

  const int dcol = lane & 15;
  const int drow = (lane >> 4) * 4;
#pragma unroll
  for (int f = 0; f < 4; ++f) {
    const int o = o0 + f * 16 + dcol;
    const float bias = bfc[o];
#pragma unroll
    for (int r = 0; r < 4; ++r) {
      const int b = b0 + wave * 16 + drow + r;
      out[(size_t)b * 1024 + o] = acc[f][r] + bias;
    }
  }
}

// ---------------------------------------------------------------------------
extern "C" void kernel_launch(void* const* d_in, const int* in_sizes, int n_in,
                              void* d_out, int out_size, void* d_ws, size_t ws_size,
                              hipStream_t stream)
{
  const float* x   = (const float*)d_in[0];
  const float* Wx  = (const float*)d_in[1];
  const float* bx  = (const float*)d_in[2];
  const float* Wh  = (const float*)d_in[3];
  const float* bh  = (const float*)d_in[4];
  const float* c2c = (const float*)d_in[5];
  const float* Wfc = (const float*)d_in[6];
  const float* bfc = (const float*)d_in[7];
  float* out = (float*)d_out;

  char* ws = (char*)d_ws;
  // layout: Wxb [0,8M) | biasc @8M (16K) | hbuf @8M+64K (1M, 2x512K)
  //         ring @10M (8M, 4 x 2M) | bar @18M (4K)   — total 18.1 MB
  __hip_bfloat16* Wxb   = (__hip_bfloat16*)(ws);
  float*          biasc = (float*)(ws + (8u << 20));
  __hip_bfloat16* hbuf  = (__hip_bfloat16*)(ws + (8u << 20) + (1u << 16));
  __hip_bfloat16* ring  = (__hip_bfloat16*)(ws + (10u << 20));
  unsigned*       bar   = (unsigned*)(ws + (18u << 20));

  hipMemsetAsync(hbuf, 0, 256 * 1024 * sizeof(__hip_bfloat16), stream);
  hipMemsetAsync(bar, 0, 4096, stream);

  pack_kernel<<<1024, 256, 0, stream>>>(Wx, bx, bh, Wxb, biasc);

  {
    const float* xa = x;
    const float* wha = Wh;
    const __hip_bfloat16* wxa = Wxb;
    const float* ba = biasc;
    const float* ca = c2c;
    __hip_bfloat16* hba = hbuf;
    __hip_bfloat16* ra = ring;
    unsigned* bara = bar;
    void* args[] = { (void*)&xa, (void*)&wha, (void*)&wxa, (void*)&ba,
                     (void*)&ca, (void*)&hba, (void*)&ra, (void*)&bara };
    hipLaunchCooperativeKernel((const void*)lstm_persist, dim3(256), dim3(512),
                               args, 0, stream);
  }

  // final h = h(512) lives in hbuf[0] ((511+1)&1 == 0)
  fc_kernel<<<64, 256, 0, stream>>>(hbuf, Wfc, bfc, out);
}

// Round 11
// 9412.489 us; speedup vs baseline: 3.2210x; 1.8752x over previous
//
#include <hip/hip_runtime.h>
#include <hip/hip_bf16.h>

typedef __attribute__((ext_vector_type(8))) short short8;
typedef __attribute__((ext_vector_type(4))) float f32x4;

#define T_STEPS 512
#define BATCH   256
#define HDIM    1024
#define GDIM    4096   // 4*H

__device__ __forceinline__ float sigmoidf_(float x) {
  return 1.0f / (1.0f + __expf(-x));
}
__device__ __forceinline__ float tanh_(float x) {
  return 2.0f / (1.0f + __expf(-2.0f * x)) - 1.0f;
}
__device__ __forceinline__ short f2bf(float f) {
  __hip_bfloat16 h = __float2bfloat16(f);
  short s;
  __builtin_memcpy(&s, &h, sizeof(short));
  return s;
}

// Async global->LDS, 16B per lane. LDS dest = wave-uniform base + lane*16
// (linear); swizzle is baked into the per-lane GLOBAL source address.
__device__ __forceinline__ void gld_lds16(const __hip_bfloat16* g, void* l) {
  __builtin_amdgcn_global_load_lds(
      (const __attribute__((address_space(1))) void*)(const void*)g,
      (__attribute__((address_space(3))) void*)l, 16, 0, 0);
}

// ---------------------------------------------------------------------------
// Pack: Whb = bf16(Wh) [4096][1024]; biasc = bx + bh      (r2-verbatim)
// ---------------------------------------------------------------------------
__global__ void pack_kernel(const float* __restrict__ Wh,
                            const float* __restrict__ bx, const float* __restrict__ bh,
                            __hip_bfloat16* __restrict__ Whb,
                            float* __restrict__ biasc)
{
  const int stride = gridDim.x * blockDim.x;
  const int tid0 = blockIdx.x * blockDim.x + threadIdx.x;
  for (int i = tid0; i < GDIM * HDIM; i += stride)
    Whb[i] = __float2bfloat16(Wh[i]);
  for (int i = tid0; i < GDIM; i += stride)
    biasc[i] = bx[i] + bh[i];
}

// ---------------------------------------------------------------------------
// xg GEMM (r2-verbatim + launch_bounds(512,2)):
// xg[(t-t0)*256 + b][g] = bf16( x[b][t][:] . Wx[g][:] )
// ---------------------------------------------------------------------------
__global__ __launch_bounds__(512, 2)
void xg_gemm(const float* __restrict__ x, const float* __restrict__ Wx,
             __hip_bfloat16* __restrict__ xg, int t0)
{
  __shared__ short8 As[2][1024];
  __shared__ short8 Bs[2][1024];

  const int tid  = threadIdx.x;
  const int wave = tid >> 6;
  const int lane = tid & 63;

  const int cpx = gridDim.x >> 3;
  const int nb  = (blockIdx.x & 7) * cpx + (blockIdx.x >> 3);
  const int nt  = nb & 31;
  const int mt  = nb >> 5;

  const int trel  = mt >> 1;
  const int brow0 = (mt & 1) * 128;

  const int r0 = tid >> 3;
  const int cg = tid & 7;

  const float* asrc0 = x + ((size_t)(brow0 + r0) * T_STEPS + (t0 + trel)) * 1024 + cg * 8;
  const float* asrc1 = x + ((size_t)(brow0 + r0 + 64) * T_STEPS + (t0 + trel)) * 1024 + cg * 8;
  const float* bsrc0 = Wx + (size_t)(nt * 128 + r0) * 1024 + cg * 8;
  const float* bsrc1 = Wx + (size_t)(nt * 128 + r0 + 64) * 1024 + cg * 8;

  const int aslot0 = r0 * 8 + (cg ^ (r0 & 7));
  const int aslot1 = (r0 + 64) * 8 + (cg ^ (r0 & 7));

  f32x4 a0l, a0h, a1l, a1h, b0l, b0h, b1l, b1h;

#define XG_LOAD(KC)                                        \
  do {                                                     \
    a0l = *(const f32x4*)(asrc0 + (KC) * 64);              \
    a0h = *(const f32x4*)(asrc0 + (KC) * 64 + 4);          \
    a1l = *(const f32x4*)(asrc1 + (KC) * 64);              \
    a1h = *(const f32x4*)(asrc1 + (KC) * 64 + 4);          \
    b0l = *(const f32x4*)(bsrc0 + (KC) * 64);              \
    b0h = *(const f32x4*)(bsrc0 + (KC) * 64 + 4);          \
    b1l = *(const f32x4*)(bsrc1 + (KC) * 64);              \
    b1h = *(const f32x4*)(bsrc1 + (KC) * 64 + 4);          \
  } while (0)

#define XG_CVT1(lo, hi, dstarr, slot)                      \
  do {                                                     \
    short8 s_;                                             \
    _Pragma("unroll")                                      \
    for (int e = 0; e < 4; ++e) {                          \
      s_[e]     = f2bf((lo)[e]);                           \
      s_[e + 4] = f2bf((hi)[e]);                           \
    }                                                      \
    dstarr[slot] = s_;                                     \
  } while (0)

#define XG_WRITE(BUF)                                      \
  do {                                                     \
    XG_CVT1(a0l, a0h, As[BUF], aslot0);                    \
    XG_CVT1(a1l, a1h, As[BUF], aslot1);                    \
    XG_CVT1(b0l, b0h, Bs[BUF], aslot0);                    \
    XG_CVT1(b1l, b1h, Bs[BUF], aslot1);                    \
  } while (0)

  const int wr = wave >> 2;
  const int wc = wave & 3;

  f32x4 acc[4][2];
#pragma unroll
  for (int m = 0; m < 4; ++m)
#pragma unroll
    for (int n = 0; n < 2; ++n) acc[m][n] = (f32x4){0.f, 0.f, 0.f, 0.f};

  XG_LOAD(0);
  XG_WRITE(0);
  __syncthreads();

#pragma unroll 1
  for (int kc = 0; kc < 16; ++kc) {
    if (kc < 15) XG_LOAD(kc + 1);
    const int bs = kc & 1;
#pragma unroll
    for (int ks = 0; ks < 2; ++ks) {
      const int cgf = ks * 4 + (lane >> 4);
      short8 af[4], bfr[2];
#pragma unroll
      for (int m = 0; m < 4; ++m) {
        const int row = wr * 64 + m * 16 + (lane & 15);
        af[m] = As[bs][row * 8 + (cgf ^ (row & 7))];
      }
#pragma unroll
      for (int n = 0; n < 2; ++n) {
        const int row = wc * 32 + n * 16 + (lane & 15);
        bfr[n] = Bs[bs][row * 8 + (cgf ^ (row & 7))];
      }
#pragma unroll
      for (int m = 0; m < 4; ++m)
#pragma unroll
        for (int n = 0; n < 2; ++n)
          acc[m][n] = __builtin_amdgcn_mfma_f32_16x16x32_bf16(af[m], bfr[n], acc[m][n], 0, 0, 0);
    }
    if (kc < 15) XG_WRITE((kc + 1) & 1);
    __syncthreads();
  }

  const int dcol = lane & 15;
  const int dr0  = (lane >> 4) * 4;
#pragma unroll
  for (int m = 0; m < 4; ++m) {
#pragma unroll
    for (int n = 0; n < 2; ++n) {
      const int ocol = nt * 128 + wc * 32 + n * 16 + dcol;
#pragma unroll
      for (int rr = 0; rr < 4; ++rr) {
        const int orow = mt * 128 + wr * 64 + m * 16 + dr0 + rr;
        xg[(size_t)orow * GDIM + ocol] = __float2bfloat16(acc[m][n][rr]);
      }
    }
  }
#undef XG_LOAD
#undef XG_CVT1
#undef XG_WRITE
}

// ---------------------------------------------------------------------------
// LSTM step (r2 dataflow; re-engineered inner loop):
//   gates = h_in @ Whb^T + xg_t + biasc; peephole cell; write h,c.
// Grid 256 x 512. Tile 64 batch x 64 cols (16 j x 4 gates). K=1024,
// BK=64 (16 chunks), LDS 32 KB dbuf (red aliases As), staging via
// global_load_lds w=16 with pre-swizzled global source, 1 barrier/chunk.
// ---------------------------------------------------------------------------
__global__ __launch_bounds__(512, 4)
void lstm_step(const __hip_bfloat16* __restrict__ xg_t,   // [256][4096]
               const __hip_bfloat16* __restrict__ Whb,    // [4096][1024]
               const float* __restrict__ biasc,
               const float* __restrict__ c2c,
               const __hip_bfloat16* __restrict__ h_in,
               __hip_bfloat16* __restrict__ h_out,
               float* __restrict__ c_st)
{
  __shared__ short8 As[2][512];   // 16 KB: 64 rows x 8 granules, dbuf
  __shared__ short8 Bs[2][512];   // 16 KB

  const int tid  = threadIdx.x;
  const int wave = tid >> 6;
  const int lane = tid & 63;
  const int l15  = lane & 15;
  const int lg   = lane >> 4;

  // r2 block mapping (XCD-aware j-tiling: perf heuristic only)
  const int bid   = blockIdx.x;
  const int xcd   = bid & 7;
  const int idx   = bid >> 3;
  const int ntile = xcd * 8 + (idx & 7);   // 0..63
  const int mtile = idx >> 3;              // 0..3
  const int b0 = mtile * 64;
  const int j0 = ntile * 16;

  // ---- staging: thread owns LDS slot tid = (row=tid>>3, cg=tid&7).
  // Source granule is cg ^ (row&7): swizzle baked into the global address.
  const int srow = tid >> 3;
  const int scg  = tid & 7;
  const int sswz = scg ^ (srow & 7);
  const __hip_bfloat16* asrc = h_in + (size_t)(b0 + srow) * HDIM + sswz * 8;
  const int bgrow = (srow >> 4) * HDIM + j0 + (srow & 15);   // gate*1024 + j
  const __hip_bfloat16* bsrc = Whb + (size_t)bgrow * HDIM + sswz * 8;

  void* la0 = (void*)&As[0][wave * 64];   // wave-uniform LDS bases
  void* la1 = (void*)&As[1][wave * 64];
  void* lb0 = (void*)&Bs[0][wave * 64];
  void* lb1 = (void*)&Bs[1][wave * 64];

  // ---- compute geometry: wave = (rf 0..3) x (kh 0..1) ----
  const int rf = wave & 3;
  const int kh = wave >> 2;
  const int arow = rf * 16 + l15;
  const int colg = kh * 4 + lg;                  // granule within 64-k chunk
  const int aidx = arow * 8 + (colg ^ (arow & 7));
  int bidx[4];
#pragma unroll
  for (int f = 0; f < 4; ++f) {
    const int br = f * 16 + l15;
    bidx[f] = br * 8 + (colg ^ (br & 7));
  }

  f32x4 acc[4];
#pragma unroll
  for (int f = 0; f < 4; ++f) acc[f] = (f32x4){0.f, 0.f, 0.f, 0.f};

  // prologue: stage chunk 0 into buf 0
  gld_lds16(asrc, la0);
  gld_lds16(bsrc, lb0);
  __syncthreads();

#pragma unroll
  for (int kc = 0; kc < 16; ++kc) {
    if (kc < 15) {
      // issue chunk kc+1 into buf (kc+1)&1 (its reads finished last iter)
      gld_lds16(asrc + (kc + 1) * 64, (kc & 1) ? la0 : la1);
      gld_lds16(bsrc + (kc + 1) * 64, (kc & 1) ? lb0 : lb1);
    }
    const short8* Ab = As[kc & 1];
    const short8* Bb = Bs[kc & 1];
    short8 af = Ab[aidx];
    acc[0] = __builtin_amdgcn_mfma_f32_16x16x32_bf16(af, Bb[bidx[0]], acc[0], 0, 0, 0);
    acc[1] = __builtin_amdgcn_mfma_f32_16x16x32_bf16(af, Bb[bidx[1]], acc[1], 0, 0, 0);
    acc[2] = __builtin_amdgcn_mfma_f32_16x16x32_bf16(af, Bb[bidx[2]], acc[2], 0, 0, 0);
    acc[3] = __builtin_amdgcn_mfma_f32_16x16x32_bf16(af, Bb[bidx[3]], acc[3], 0, 0, 0);
    __syncthreads();   // drains glds (vmcnt) + ds_reads (lgkm)
  }

  // ---- k-half reduction through As alias (exactly 16 KB), then cell ----
  float* red = (float*)&As[0][0];
  const int drow = lg * 4;
  const int dcol = l15;
  if (kh == 1) {
#pragma unroll
    for (int f = 0; f < 4; ++f)
#pragma unroll
      for (int r = 0; r < 4; ++r)
        red[(rf * 16 + drow + r) * 64 + f * 16 + dcol] = acc[f][r];
  }
  __syncthreads();
  if (kh == 0) {
#pragma unroll
    for (int f = 0; f < 4; ++f)
#pragma unroll
      for (int r = 0; r < 4; ++r)
        acc[f][r] += red[(rf * 16 + drow + r) * 64 + f * 16 + dcol];

    const int j = j0 + dcol;
    const float bi = biasc[j];
    const float bf = biasc[HDIM + j];
    const float bg = biasc[2 * HDIM + j];
    const float bo = biasc[3 * HDIM + j];
    const float ci = c2c[j];
    const float cf = c2c[HDIM + j];
    const float co = c2c[2 * HDIM + j];
#pragma unroll
    for (int r = 0; r < 4; ++r) {
      const int b = b0 + rf * 16 + drow + r;
      const __hip_bfloat16* xr = xg_t + (size_t)b * GDIM + j;
      float x0 = __bfloat162float(xr[0]);
      float x1 = __bfloat162float(xr[HDIM]);
      float x2 = __bfloat162float(xr[2 * HDIM]);
      float x3 = __bfloat162float(xr[3 * HDIM]);
      float cp = c_st[(size_t)b * HDIM + j];
      float ig = sigmoidf_(acc[0][r] + x0 + bi + ci * cp);
      float fg = sigmoidf_(acc[1][r] + x1 + bf + cf * cp);
      float gg = tanh_(acc[2][r] + x2 + bg);
      float cn = fg * cp + ig * gg;
      float og = sigmoidf_(acc[3][r] + x3 + bo + co * cn);
      float hn = og * tanh_(cn);
      c_st[(size_t)b * HDIM + j] = cn;
      h_out[(size_t)b * HDIM + j] = __float2bfloat16(hn);
    }
  }
}

// ---------------------------------------------------------------------------
// Final FC (r2-verbatim): out[b][o] = h[b][:] . Wfc[o][:] + bfc[o]
// ---------------------------------------------------------------------------
__global__ __launch_bounds__(256, 1)
void fc_kernel(const __hip_bfloat16* __restrict__ h,
               const float* __restrict__ Wfc,
               const float* __restrict__ bfc,
               float* __restrict__ out)
{
  __shared__ short8 As8[512];
  __shared__ short8 Bs8[512];

  const int tid = threadIdx.x;
  const int wave = tid >> 6;
  const int lane = tid & 63;
  const int mtile = blockIdx.x >> 4;
  const int otile = blockIdx.x & 15;
  const int b0 = mtile * 64, o0 = otile * 64;

  const int r0 = tid >> 3;
  const int cg0 = tid & 7;

  f32x4 acc[4];
#pragma unroll
  for (int f = 0; f < 4; ++f) acc[f] = (f32x4){0.f, 0.f, 0.f, 0.f};

#pragma unroll 1
  for (int kc = 0; kc < 16; ++kc) {
    __syncthreads();
    As8[r0 * 8 + (cg0 ^ (r0 & 7))] =
        *(const short8*)(const void*)(h + (size_t)(b0 + r0) * HDIM + kc * 64 + cg0 * 8);
    As8[(r0 + 32) * 8 + (cg0 ^ (r0 & 7))] =
        *(const short8*)(const void*)(h + (size_t)(b0 + r0 + 32) * HDIM + kc * 64 + cg0 * 8);
    {
      const float* p0 = Wfc + (size_t)(o0 + r0) * HDIM + kc * 64 + cg0 * 8;
      const float* p1 = Wfc + (size_t)(o0 + r0 + 32) * HDIM + kc * 64 + cg0 * 8;
      f32x4 l0 = *(const f32x4*)p0, h0 = *(const f32x4*)(p0 + 4);
      f32x4 l1 = *(const f32x4*)p1, h1 = *(const f32x4*)(p1 + 4);
      short8 s0, s1;
#pragma unroll
      for (int e = 0; e < 4; ++e) {
        s0[e] = f2bf(l0[e]); s0[e + 4] = f2bf(h0[e]);
        s1[e] = f2bf(l1[e]); s1[e + 4] = f2bf(h1[e]);
      }
      Bs8[r0 * 8 + (cg0 ^ (r0 & 7))] = s0;
      Bs8[(r0 + 32) * 8 + (cg0 ^ (r0 & 7))] = s1;
    }
    __syncthreads();
#pragma unroll
    for (int s = 0; s < 2; ++s) {
      const int colg = s * 4 + (lane >> 4);
      const int ar = wave * 16 + (lane & 15);
      short8 af = As8[ar * 8 + (colg ^ (ar & 7))];
#pragma unroll
      for (int f = 0; f < 4; ++f) {
        const int br = f * 16 + (lane & 15);
        short8 bfq = Bs8[br * 8 + (colg ^ (br & 7))];
        acc[f] = __builtin_amdgcn_mfma_f32_16x16x32_bf16(af, bfq, acc[f], 0, 0, 0);
      }
    }
  }

  const int dcol = lane & 15;
  const int drow = (lane >> 4) * 4;
#pragma unroll
  for (int f = 0; f < 4; ++f) {
    const int o = o0 + f * 16 + dcol;
    const float bias = bfc[o];
#pragma unroll
    for (int r = 0; r < 4; ++r) {
      const int b = b0 + wave * 16 + drow + r;
      out[(size_t)b * 1024 + o] = acc[f][r] + bias;
    }
  }
}

// ---------------------------------------------------------------------------
extern "C" void kernel_launch(void* const* d_in, const int* in_sizes, int n_in,
                              void* d_out, int out_size, void* d_ws, size_t ws_size,
                              hipStream_t stream)
{
  const float* x   = (const float*)d_in[0];
  const float* Wx  = (const float*)d_in[1];
  const float* bx  = (const float*)d_in[2];
  const float* Wh  = (const float*)d_in[3];
  const float* bh  = (const float*)d_in[4];
  const float* c2c = (const float*)d_in[5];
  const float* Wfc = (const float*)d_in[6];
  const float* bfc = (const float*)d_in[7];
  float* out = (float*)d_out;

  char* ws = (char*)d_ws;
  // layout (r2-verbatim):
  //   [0, 8M)            Whb bf16 [4096][1024]
  //   [8M, 8M+16K)       biasc f32 [4096]
  //   [8M+64K, +512K)    hb0
  //   [.. +512K)         hb1
  //   [8M+64K+1M, +1M)   c_st f32
  //   [11M, ...)         xg ring: W * 256 * 4096 bf16  (W*2MB)
  __hip_bfloat16* Whb   = (__hip_bfloat16*)(ws);
  float*          biasc = (float*)(ws + (8u << 20));
  __hip_bfloat16* hb0   = (__hip_bfloat16*)(ws + (8u << 20) + (1u << 16));
  __hip_bfloat16* hb1   = (__hip_bfloat16*)(ws + (8u << 20) + (1u << 16) + (1u << 19));
  float*          c_st  = (float*)(ws + (8u << 20) + (1u << 16) + (1u << 20));
  __hip_bfloat16* xgbuf = (__hip_bfloat16*)(ws + (11u << 20));

  // adaptive window: largest divisor of 512 whose ring fits in ws
  const size_t xg_off = (size_t)11 << 20;
  int W = 4;
  for (int cand = 512; cand >= 4; cand >>= 1) {
    size_t need = xg_off + (size_t)cand * BATCH * GDIM * sizeof(__hip_bfloat16);
    if (need <= ws_size) { W = cand; break; }
  }

  hipMemsetAsync(hb0, 0, (size_t)BATCH * HDIM * sizeof(__hip_bfloat16), stream);
  hipMemsetAsync(c_st, 0, (size_t)BATCH * HDIM * sizeof(float), stream);

  pack_kernel<<<1024, 256, 0, stream>>>(Wh, bx, bh, Whb, biasc);

  const int NW = T_STEPS / W;
  for (int w = 0; w < NW; ++w) {
    xg_gemm<<<W * 64, 512, 0, stream>>>(x, Wx, xgbuf, w * W);
    for (int tt = 0; tt < W; ++tt) {
      const int t = w * W + tt;
      const __hip_bfloat16* hin = (t & 1) ? hb1 : hb0;
      __hip_bfloat16* hout      = (t & 1) ? hb0 : hb1;
      lstm_step<<<256, 512, 0, stream>>>(xgbuf + (size_t)tt * BATCH * GDIM,
                                         Whb, biasc, c2c, hin, hout, c_st);
    }
  }

  fc_kernel<<<64, 256, 0, stream>>>(hb0, Wfc, bfc, out);
}

// Round 12
// 8273.442 us; speedup vs baseline: 3.6645x; 1.1377x over previous
//
#include <hip/hip_runtime.h>
#include <hip/hip_bf16.h>
#include <stdint.h>

typedef __attribute__((ext_vector_type(8))) short short8;
typedef __attribute__((ext_vector_type(4))) float f32x4;

#define T_STEPS 512
#define BATCH   256
#define HDIM    1024
#define GDIM    4096   // 4*H

__device__ __forceinline__ float sigmoidf_(float x) {
  return 1.0f / (1.0f + __expf(-x));
}
__device__ __forceinline__ float tanh_(float x) {
  return 2.0f / (1.0f + __expf(-2.0f * x)) - 1.0f;
}
__device__ __forceinline__ short f2bf(float f) {
  __hip_bfloat16 h = __float2bfloat16(f);
  short s;
  __builtin_memcpy(&s, &h, sizeof(short));
  return s;
}
__device__ __forceinline__ float bf2f(unsigned u16) {
  unsigned u = u16 << 16;
  float f;
  __builtin_memcpy(&f, &u, 4);
  return f;
}

// inline-asm 16B load: opaque to the compiler -> result stays in VGPRs
#define AL16(dst, off, base)                                        \
  asm volatile("global_load_dwordx4 %0, %1, %2"                     \
               : "=v"(dst) : "v"(off), "s"(base) : "memory")
#define VMDRAIN() asm volatile("s_waitcnt vmcnt(0)" ::: "memory")

// Async global->LDS, 16B/lane: LDS dest = wave-uniform base + lane*16
__device__ __forceinline__ void gld_lds16(const __hip_bfloat16* g, void* l) {
  __builtin_amdgcn_global_load_lds(
      (const __attribute__((address_space(1))) void*)(const void*)g,
      (__attribute__((address_space(3))) void*)l, 16, 0, 0);
}

// ---------------------------------------------------------------------------
// Pack: Whb = bf16(Wh) [4096][1024]; biasc = bx + bh      (r2-verbatim)
// ---------------------------------------------------------------------------
__global__ void pack_kernel(const float* __restrict__ Wh,
                            const float* __restrict__ bx, const float* __restrict__ bh,
                            __hip_bfloat16* __restrict__ Whb,
                            float* __restrict__ biasc)
{
  const int stride = gridDim.x * blockDim.x;
  const int tid0 = blockIdx.x * blockDim.x + threadIdx.x;
  for (int i = tid0; i < GDIM * HDIM; i += stride)
    Whb[i] = __float2bfloat16(Wh[i]);
  for (int i = tid0; i < GDIM; i += stride)
    biasc[i] = bx[i] + bh[i];
}

// ---------------------------------------------------------------------------
// xg GEMM (r2-exact, launch_bounds(512,1)):
// xg[(t-t0)*256 + b][g] = bf16( x[b][t][:] . Wx[g][:] )
// ---------------------------------------------------------------------------
__global__ __launch_bounds__(512, 1)
void xg_gemm(const float* __restrict__ x, const float* __restrict__ Wx,
             __hip_bfloat16* __restrict__ xg, int t0)
{
  __shared__ short8 As[2][1024];
  __shared__ short8 Bs[2][1024];

  const int tid  = threadIdx.x;
  const int wave = tid >> 6;
  const int lane = tid & 63;

  const int cpx = gridDim.x >> 3;
  const int nb  = (blockIdx.x & 7) * cpx + (blockIdx.x >> 3);
  const int nt  = nb & 31;
  const int mt  = nb >> 5;

  const int trel  = mt >> 1;
  const int brow0 = (mt & 1) * 128;

  const int r0 = tid >> 3;
  const int cg = tid & 7;

  const float* asrc0 = x + ((size_t)(brow0 + r0) * T_STEPS + (t0 + trel)) * 1024 + cg * 8;
  const float* asrc1 = x + ((size_t)(brow0 + r0 + 64) * T_STEPS + (t0 + trel)) * 1024 + cg * 8;
  const float* bsrc0 = Wx + (size_t)(nt * 128 + r0) * 1024 + cg * 8;
  const float* bsrc1 = Wx + (size_t)(nt * 128 + r0 + 64) * 1024 + cg * 8;

  const int aslot0 = r0 * 8 + (cg ^ (r0 & 7));
  const int aslot1 = (r0 + 64) * 8 + (cg ^ (r0 & 7));

  f32x4 a0l, a0h, a1l, a1h, b0l, b0h, b1l, b1h;

#define XG_LOAD(KC)                                        \
  do {                                                     \
    a0l = *(const f32x4*)(asrc0 + (KC) * 64);              \
    a0h = *(const f32x4*)(asrc0 + (KC) * 64 + 4);          \
    a1l = *(const f32x4*)(asrc1 + (KC) * 64);              \
    a1h = *(const f32x4*)(asrc1 + (KC) * 64 + 4);          \
    b0l = *(const f32x4*)(bsrc0 + (KC) * 64);              \
    b0h = *(const f32x4*)(bsrc0 + (KC) * 64 + 4);          \
    b1l = *(const f32x4*)(bsrc1 + (KC) * 64);              \
    b1h = *(const f32x4*)(bsrc1 + (KC) * 64 + 4);          \
  } while (0)

#define XG_CVT1(lo, hi, dstarr, slot)                      \
  do {                                                     \
    short8 s_;                                             \
    _Pragma("unroll")                                      \
    for (int e = 0; e < 4; ++e) {                          \
      s_[e]     = f2bf((lo)[e]);                           \
      s_[e + 4] = f2bf((hi)[e]);                           \
    }                                                      \
    dstarr[slot] = s_;                                     \
  } while (0)

#define XG_WRITE(BUF)                                      \
  do {                                                     \
    XG_CVT1(a0l, a0h, As[BUF], aslot0);                    \
    XG_CVT1(a1l, a1h, As[BUF], aslot1);                    \
    XG_CVT1(b0l, b0h, Bs[BUF], aslot0);                    \
    XG_CVT1(b1l, b1h, Bs[BUF], aslot1);                    \
  } while (0)

  const int wr = wave >> 2;
  const int wc = wave & 3;

  f32x4 acc[4][2];
#pragma unroll
  for (int m = 0; m < 4; ++m)
#pragma unroll
    for (int n = 0; n < 2; ++n) acc[m][n] = (f32x4){0.f, 0.f, 0.f, 0.f};

  XG_LOAD(0);
  XG_WRITE(0);
  __syncthreads();

#pragma unroll 1
  for (int kc = 0; kc < 16; ++kc) {
    if (kc < 15) XG_LOAD(kc + 1);
    const int bs = kc & 1;
#pragma unroll
    for (int ks = 0; ks < 2; ++ks) {
      const int cgf = ks * 4 + (lane >> 4);
      short8 af[4], bfr[2];
#pragma unroll
      for (int m = 0; m < 4; ++m) {
        const int row = wr * 64 + m * 16 + (lane & 15);
        af[m] = As[bs][row * 8 + (cgf ^ (row & 7))];
      }
#pragma unroll
      for (int n = 0; n < 2; ++n) {
        const int row = wc * 32 + n * 16 + (lane & 15);
        bfr[n] = Bs[bs][row * 8 + (cgf ^ (row & 7))];
      }
#pragma unroll
      for (int m = 0; m < 4; ++m)
#pragma unroll
        for (int n = 0; n < 2; ++n)
          acc[m][n] = __builtin_amdgcn_mfma_f32_16x16x32_bf16(af[m], bfr[n], acc[m][n], 0, 0, 0);
    }
    if (kc < 15) XG_WRITE((kc + 1) & 1);
    __syncthreads();
  }

  const int dcol = lane & 15;
  const int dr0  = (lane >> 4) * 4;
#pragma unroll
  for (int m = 0; m < 4; ++m) {
#pragma unroll
    for (int n = 0; n < 2; ++n) {
      const int ocol = nt * 128 + wc * 32 + n * 16 + dcol;
#pragma unroll
      for (int rr = 0; rr < 4; ++rr) {
        const int orow = mt * 128 + wr * 64 + m * 16 + dr0 + rr;
        xg[(size_t)orow * GDIM + ocol] = __float2bfloat16(acc[m][n][rr]);
      }
    }
  }
#undef XG_LOAD
#undef XG_CVT1
#undef XG_WRITE
}

// ---------------------------------------------------------------------------
// LSTM step, lean pipeline:
//   gates = h_in @ Whb^T + xg_t + biasc; peephole cell; write h,c.
// Grid 256 x 512. Tile 64 batch x 16 j x 4 gates. Waves = (gate 0..3, kh 0..1).
// B (Wh frags) pinned in VGPRs via asm loads (64 VGPR/wave, no LDS for B).
// A (h slice, 128 KB) staged ONCE via global_load_lds w=16, pre-swizzled src.
// kh halves write DISJOINT red regions -> 3 barriers/step total.
// ---------------------------------------------------------------------------
__global__ __launch_bounds__(512, 1)
void lstm_step(const __hip_bfloat16* __restrict__ xg_t,   // [256][4096]
               const __hip_bfloat16* __restrict__ Whb,    // [4096][1024]
               const float* __restrict__ biasc,
               const float* __restrict__ c2c,
               const __hip_bfloat16* __restrict__ h_in,
               __hip_bfloat16* __restrict__ h_out,
               float* __restrict__ c_st)
{
  __shared__ short8 hstage[8192];   // 128 KB; red regions alias the front later

  const int tid  = threadIdx.x;
  const int wave = tid >> 6;
  const int lane = tid & 63;
  const int l15  = lane & 15;
  const int lg   = lane >> 4;

  // block mapping (r2's XCD-aware j-tiling; perf heuristic only)
  const int bid   = blockIdx.x;
  const int xcd   = bid & 7;
  const int idx   = bid >> 3;
  const int ntile = xcd * 8 + (idx & 7);   // 0..63
  const int mtile = idx >> 3;              // 0..3
  const int b0 = mtile * 64;
  const int j0 = ntile * 16;

  const int gate = wave >> 1;
  const int kh   = wave & 1;

  // ---- B fragments -> VGPRs (asm, not rematerializable) ----
  // rows gate*1024 + j0 + l15 ; cols kh*512 + c*32 + lg*8
  short8 bw[16];
  {
    const uint64_t base = (uint64_t)Whb;
    const unsigned off0 =
        (unsigned)((((gate * 1024 + j0 + l15) * 1024) + kh * 512 + lg * 8) * 2);
#pragma unroll
    for (int c = 0; c < 16; ++c)
      AL16(bw[c], off0 + (unsigned)(c * 64), base);
  }

  // ---- A: stage h slice (64 rows x 1024) via glds, source-swizzled ----
#pragma unroll
  for (int k = 0; k < 16; ++k) {
    const int gidx = tid + k * 512;          // linear granule id
    const int row  = gidx >> 7;
    const int gc   = gidx & 127;
    gld_lds16(h_in + (size_t)(b0 + row) * HDIM + (gc ^ (row & 7)) * 8,
              (void*)&hstage[k * 512 + wave * 64]);
  }
  VMDRAIN();                               // drains bw asm loads + glds
  __builtin_amdgcn_sched_barrier(0);       // rule #18: pin MFMA after drain
  __syncthreads();

  // ---- MFMA sweep: A from LDS, B from registers ----
  f32x4 acc[4];
#pragma unroll
  for (int m = 0; m < 4; ++m) acc[m] = (f32x4){0.f, 0.f, 0.f, 0.f};

#pragma unroll
  for (int c = 0; c < 16; ++c) {
    const int colg = kh * 64 + c * 4 + lg;
#pragma unroll
    for (int m = 0; m < 4; ++m) {
      const int row = m * 16 + l15;
      short8 af = hstage[row * 128 + (colg ^ (row & 7))];
      acc[m] = __builtin_amdgcn_mfma_f32_16x16x32_bf16(af, bw[c], acc[m], 0, 0, 0);
    }
  }
  __syncthreads();   // all A reads done; safe to alias red over hstage

  // ---- write partials: kh regions disjoint, one barrier ----
  float* redA = (float*)&hstage[0];        // [4][64][18] f32 = 18 KB
  float* redB = redA + 4608;               // second 18 KB
  {
    float* myred = kh ? redB : redA;
#pragma unroll
    for (int m = 0; m < 4; ++m)
#pragma unroll
      for (int r = 0; r < 4; ++r)
        myred[gate * 1152 + (m * 16 + lg * 4 + r) * 18 + l15] = acc[m][r];
  }
  __syncthreads();

  // ---- fused peephole cell: 512 threads x 2 cells ----
  {
    const int row = tid >> 3;            // 0..63
    const int c2  = (tid & 7) * 2;       // 0..14
    const int j   = j0 + c2;
    const int b   = b0 + row;

    float g0[4], g1[4];
#pragma unroll
    for (int gg = 0; gg < 4; ++gg) {
      const int o = gg * 1152 + row * 18 + c2;
      unsigned u  = *(const unsigned*)&xg_t[(size_t)b * GDIM + gg * 1024 + j];
      g0[gg] = redA[o]     + redB[o]     + biasc[gg * 1024 + j]     + bf2f(u & 0xffffu);
      g1[gg] = redA[o + 1] + redB[o + 1] + biasc[gg * 1024 + j + 1] + bf2f(u >> 16);
    }
    const float ci0 = c2c[j],            ci1 = c2c[j + 1];
    const float cf0 = c2c[HDIM + j],     cf1 = c2c[HDIM + j + 1];
    const float co0 = c2c[2 * HDIM + j], co1 = c2c[2 * HDIM + j + 1];

    float cp0 = c_st[(size_t)b * HDIM + j];
    float cp1 = c_st[(size_t)b * HDIM + j + 1];

    float ii = sigmoidf_(g0[0] + ci0 * cp0);
    float ff = sigmoidf_(g0[1] + cf0 * cp0);
    float gv = tanh_(g0[2]);
    float cn0 = ff * cp0 + ii * gv;
    float oo = sigmoidf_(g0[3] + co0 * cn0);
    float h0 = oo * tanh_(cn0);

    ii = sigmoidf_(g1[0] + ci1 * cp1);
    ff = sigmoidf_(g1[1] + cf1 * cp1);
    gv = tanh_(g1[2]);
    float cn1 = ff * cp1 + ii * gv;
    oo = sigmoidf_(g1[3] + co1 * cn1);
    float h1 = oo * tanh_(cn1);

    c_st[(size_t)b * HDIM + j]     = cn0;
    c_st[(size_t)b * HDIM + j + 1] = cn1;
    unsigned pk = (unsigned)(unsigned short)f2bf(h0) |
                  ((unsigned)(unsigned short)f2bf(h1) << 16);
    *(unsigned*)&h_out[(size_t)b * HDIM + j] = pk;
  }
}

// ---------------------------------------------------------------------------
// Final FC (r2-verbatim): out[b][o] = h[b][:] . Wfc[o][:] + bfc[o]
// ---------------------------------------------------------------------------
__global__ __launch_bounds__(256, 1)
void fc_kernel(const __hip_bfloat16* __restrict__ h,
               const float* __restrict__ Wfc,
               const float* __restrict__ bfc,
               float* __restrict__ out)
{
  __shared__ short8 As8[512];
  __shared__ short8 Bs8[512];

  const int tid = threadIdx.x;
  const int wave = tid >> 6;
  const int lane = tid & 63;
  const int mtile = blockIdx.x >> 4;
  const int otile = blockIdx.x & 15;
  const int b0 = mtile * 64, o0 = otile * 64;

  const int r0 = tid >> 3;
  const int cg0 = tid & 7;

  f32x4 acc[4];
#pragma unroll
  for (int f = 0; f < 4; ++f) acc[f] = (f32x4){0.f, 0.f, 0.f, 0.f};

#pragma unroll 1
  for (int kc = 0; kc < 16; ++kc) {
    __syncthreads();
    As8[r0 * 8 + (cg0 ^ (r0 & 7))] =
        *(const short8*)(const void*)(h + (size_t)(b0 + r0) * HDIM + kc * 64 + cg0 * 8);
    As8[(r0 + 32) * 8 + (cg0 ^ (r0 & 7))] =
        *(const short8*)(const void*)(h + (size_t)(b0 + r0 + 32) * HDIM + kc * 64 + cg0 * 8);
    {
      const float* p0 = Wfc + (size_t)(o0 + r0) * HDIM + kc * 64 + cg0 * 8;
      const float* p1 = Wfc + (size_t)(o0 + r0 + 32) * HDIM + kc * 64 + cg0 * 8;
      f32x4 l0 = *(const f32x4*)p0, h0 = *(const f32x4*)(p0 + 4);
      f32x4 l1 = *(const f32x4*)p1, h1 = *(const f32x4*)(p1 + 4);
      short8 s0, s1;
#pragma unroll
      for (int e = 0; e < 4; ++e) {
        s0[e] = f2bf(l0[e]); s0[e + 4] = f2bf(h0[e]);
        s1[e] = f2bf(l1[e]); s1[e + 4] = f2bf(h1[e]);
      }
      Bs8[r0 * 8 + (cg0 ^ (r0 & 7))] = s0;
      Bs8[(r0 + 32) * 8 + (cg0 ^ (r0 & 7))] = s1;
    }
    __syncthreads();
#pragma unroll
    for (int s = 0; s < 2; ++s) {
      const int colg = s * 4 + (lane >> 4);
      const int ar = wave * 16 + (lane & 15);
      short8 af = As8[ar * 8 + (colg ^ (ar & 7))];
#pragma unroll
      for (int f = 0; f < 4; ++f) {
        const int br = f * 16 + (lane & 15);
        short8 bfq = Bs8[br * 8 + (colg ^ (br & 7))];
        acc[f] = __builtin_amdgcn_mfma_f32_16x16x32_bf16(af, bfq, acc[f], 0, 0, 0);
      }
    }
  }

  const int dcol = lane & 15;
  const int drow = (lane >> 4) * 4;
#pragma unroll
  for (int f = 0; f < 4; ++f) {
    const int o = o0 + f * 16 + dcol;
    const float bias = bfc[o];
#pragma unroll
    for (int r = 0; r < 4; ++r) {
      const int b = b0 + wave * 16 + drow + r;
      out[(size_t)b * 1024 + o] = acc[f][r] + bias;
    }
  }
}

// ---------------------------------------------------------------------------
extern "C" void kernel_launch(void* const* d_in, const int* in_sizes, int n_in,
                              void* d_out, int out_size, void* d_ws, size_t ws_size,
                              hipStream_t stream)
{
  const float* x   = (const float*)d_in[0];
  const float* Wx  = (const float*)d_in[1];
  const float* bx  = (const float*)d_in[2];
  const float* Wh  = (const float*)d_in[3];
  const float* bh  = (const float*)d_in[4];
  const float* c2c = (const float*)d_in[5];
  const float* Wfc = (const float*)d_in[6];
  const float* bfc = (const float*)d_in[7];
  float* out = (float*)d_out;

  char* ws = (char*)d_ws;
  // layout (r2-verbatim):
  //   [0, 8M)            Whb bf16 [4096][1024]
  //   [8M, 8M+16K)       biasc f32 [4096]
  //   [8M+64K, +512K)    hb0
  //   [.. +512K)         hb1
  //   [8M+64K+1M, +1M)   c_st f32
  //   [11M, ...)         xg ring: W * 256 * 4096 bf16  (W*2MB)
  __hip_bfloat16* Whb   = (__hip_bfloat16*)(ws);
  float*          biasc = (float*)(ws + (8u << 20));
  __hip_bfloat16* hb0   = (__hip_bfloat16*)(ws + (8u << 20) + (1u << 16));
  __hip_bfloat16* hb1   = (__hip_bfloat16*)(ws + (8u << 20) + (1u << 16) + (1u << 19));
  float*          c_st  = (float*)(ws + (8u << 20) + (1u << 16) + (1u << 20));
  __hip_bfloat16* xgbuf = (__hip_bfloat16*)(ws + (11u << 20));

  // adaptive window: largest divisor of 512 whose ring fits in ws
  const size_t xg_off = (size_t)11 << 20;
  int W = 4;
  for (int cand = 512; cand >= 4; cand >>= 1) {
    size_t need = xg_off + (size_t)cand * BATCH * GDIM * sizeof(__hip_bfloat16);
    if (need <= ws_size) { W = cand; break; }
  }

  hipMemsetAsync(hb0, 0, (size_t)BATCH * HDIM * sizeof(__hip_bfloat16), stream);
  hipMemsetAsync(c_st, 0, (size_t)BATCH * HDIM * sizeof(float), stream);

  pack_kernel<<<1024, 256, 0, stream>>>(Wh, bx, bh, Whb, biasc);

  const int NW = T_STEPS / W;
  for (int w = 0; w < NW; ++w) {
    xg_gemm<<<W * 64, 512, 0, stream>>>(x, Wx, xgbuf, w * W);
    for (int tt = 0; tt < W; ++tt) {
      const int t = w * W + tt;
      const __hip_bfloat16* hin = (t & 1) ? hb1 : hb0;
      __hip_bfloat16* hout      = (t & 1) ? hb0 : hb1;
      lstm_step<<<256, 512, 0, stream>>>(xgbuf + (size_t)tt * BATCH * GDIM,
                                         Whb, biasc, c2c, hin, hout, c_st);
    }
  }

  fc_kernel<<<64, 256, 0, stream>>>(hb0, Wfc, bfc, out);
}